// Round 1
// baseline (324.722 us; speedup 1.0000x reference)
//
#include <hip/hip_runtime.h>
#include <hip/hip_bf16.h>
#include <stdint.h>

// Problem constants (from reference)
#define B_  32
#define T_  1024
#define C_  512
#define H_  1024
#define SCALE_ 32.0f   // sqrt(1024)

// Tiling
#define BM 128
#define BN 128
#define BK 32
#define ROWB 40              // padded LDS row length in bf16 elems (80 B stride -> conflict-free b128 frag reads)
#define NSTEP (C_ / BK)      // 16

typedef __attribute__((ext_vector_type(8))) short frag_ab;   // 8 bf16 (4 VGPRs)
typedef __attribute__((ext_vector_type(4))) float frag_cd;   // 4 fp32

// RNE float -> bf16 (no NaN handling; inputs are finite random data)
__device__ __forceinline__ unsigned short f2bf(float f) {
    union { float f; uint32_t u; } v; v.f = f;
    uint32_t u = v.u;
    return (unsigned short)((u + 0x7FFFu + ((u >> 16) & 1u)) >> 16);
}

__device__ __forceinline__ void cvt4_store(unsigned short* dst, float4 v) {
    union { unsigned short u[4]; uint2 d; } p;
    p.u[0] = f2bf(v.x); p.u[1] = f2bf(v.y); p.u[2] = f2bf(v.z); p.u[3] = f2bf(v.w);
    *(uint2*)dst = p.d;   // 8 B aligned: row*80 + k4*8
}

__global__ __launch_bounds__(256, 2)
void NeuralEmbeddingLayer_kernel(
    const float* __restrict__ features,     // [B,T,C]
    const int*   __restrict__ ts,           // [B,T]
    const int*   __restrict__ date_idx,     // [B]
    const float* __restrict__ spikes,       // [N_DATES,H,C]
    const float* __restrict__ spikes_bias,  // [N_DATES]
    const float* __restrict__ pos,          // [MAX_F,H]
    float*       __restrict__ out)          // [B,T,H]
{
    const int tid = threadIdx.x;
    const int bid = blockIdx.x;
    const int b     = bid >> 6;         // 64 blocks per batch sample
    const int ttile = (bid >> 3) & 7;   // h fastest -> 8 consecutive blocks share features tile (L2)
    const int htile = bid & 7;
    const int t0 = ttile * BM;
    const int h0 = htile * BN;

    const int   date = date_idx[b];
    const float bias = spikes_bias[date];
    const float* A = features + ((size_t)b * T_ + t0) * C_;     // row stride C_
    const float* W = spikes   + ((size_t)date * H_ + h0) * C_;  // row stride C_

    __shared__ __align__(16) unsigned short ldsA[2][BM * ROWB]; // 10 KB each
    __shared__ __align__(16) unsigned short ldsB[2][BM * ROWB];
    __shared__ int lds_ts[BM];

    if (tid < BM) lds_ts[tid] = ts[b * T_ + t0 + tid];

    // ---- staging helpers ----
    // tile has 128 rows x 8 float4-groups = 1024 groups; 256 threads -> 4 each
    float4 pfA[4], pfB[4];

    auto gload = [&](const float* __restrict__ base, int i, int k0) -> float4 {
        int g = i * 256 + tid;
        int row = g >> 3, k4 = g & 7;
        return *(const float4*)(base + (size_t)row * C_ + k0 + k4 * 4);
    };
    auto stage = [&](int buf) {
#pragma unroll
        for (int i = 0; i < 4; ++i) {
            int g = i * 256 + tid;
            int row = g >> 3, k4 = g & 7;
            cvt4_store(&ldsA[buf][row * ROWB + k4 * 4], pfA[i]);
            cvt4_store(&ldsB[buf][row * ROWB + k4 * 4], pfB[i]);
        }
    };

    // ---- prologue: K-step 0 ----
#pragma unroll
    for (int i = 0; i < 4; ++i) { pfA[i] = gload(A, i, 0); pfB[i] = gload(W, i, 0); }
    stage(0);
    __syncthreads();

    // ---- wave/lane decode ----
    const int wave = tid >> 6;
    const int lane = tid & 63;
    const int quad = lane >> 4;       // selects k-halfgroup for A/B frags; row-quad for C/D
    const int m_   = lane & 15;
    const int wm = (wave >> 1) * 64;  // wave tile origin in M (t)
    const int wn = (wave & 1) * 64;   // in N (h)

    frag_cd acc[4][4] = {};

    // ---- K loop: double-buffered LDS, register prefetch ----
    for (int ks = 0; ks < NSTEP; ++ks) {
        const int buf = ks & 1;
        if (ks + 1 < NSTEP) {
            const int k0 = (ks + 1) * BK;
#pragma unroll
            for (int i = 0; i < 4; ++i) { pfA[i] = gload(A, i, k0); pfB[i] = gload(W, i, k0); }
        }

        frag_ab afrag[4], bfrag[4];
#pragma unroll
        for (int mi = 0; mi < 4; ++mi) {
            int row = wm + mi * 16 + m_;
            afrag[mi] = *(const frag_ab*)&ldsA[buf][row * ROWB + quad * 8];
        }
#pragma unroll
        for (int ni = 0; ni < 4; ++ni) {
            int row = wn + ni * 16 + m_;
            bfrag[ni] = *(const frag_ab*)&ldsB[buf][row * ROWB + quad * 8];
        }
#pragma unroll
        for (int mi = 0; mi < 4; ++mi)
#pragma unroll
            for (int ni = 0; ni < 4; ++ni)
                acc[mi][ni] = __builtin_amdgcn_mfma_f32_16x16x32_bf16(
                    afrag[mi], bfrag[ni], acc[mi][ni], 0, 0, 0);

        if (ks + 1 < NSTEP) stage((ks + 1) & 1);
        __syncthreads();
    }

    // ---- epilogue: acc*SCALE + bias + pos[ts[t]][h] ----
    // C/D layout (m89-verified): col = lane&15 (n/h), row = quad*4 + reg (m/t)
#pragma unroll
    for (int mi = 0; mi < 4; ++mi) {
#pragma unroll
        for (int r = 0; r < 4; ++r) {
            int trow = wm + mi * 16 + quad * 4 + r;
            int tsv  = lds_ts[trow];
            const float* prow = pos + (size_t)tsv * H_ + h0;
            size_t orow = ((size_t)b * T_ + (t0 + trow)) * (size_t)H_ + h0;
#pragma unroll
            for (int ni = 0; ni < 4; ++ni) {
                int col = wn + ni * 16 + m_;
                out[orow + col] = acc[mi][ni][r] * SCALE_ + bias + prow[col];
            }
        }
    }
}

extern "C" void kernel_launch(void* const* d_in, const int* in_sizes, int n_in,
                              void* d_out, int out_size, void* d_ws, size_t ws_size,
                              hipStream_t stream) {
    const float* features  = (const float*)d_in[0];
    const int*   ts        = (const int*)d_in[1];
    const int*   date_idx  = (const int*)d_in[2];
    const float* spikes    = (const float*)d_in[3];
    const float* sbias     = (const float*)d_in[4];
    const float* pos       = (const float*)d_in[5];
    float*       out       = (float*)d_out;

    dim3 grid(B_ * (T_ / BM) * (H_ / BN));   // 32 * 8 * 8 = 2048
    NeuralEmbeddingLayer_kernel<<<grid, 256, 0, stream>>>(
        features, ts, date_idx, spikes, sbias, pos, out);
}

// Round 2
// 316.413 us; speedup vs baseline: 1.0263x; 1.0263x over previous
//
#include <hip/hip_runtime.h>
#include <hip/hip_bf16.h>
#include <stdint.h>

// Problem constants (from reference)
#define B_  32
#define T_  1024
#define C_  512
#define H_  1024
#define SCALE_ 32.0f   // sqrt(1024)

// Tiling
#define BM 128
#define BN 128
#define BK 32
#define ROWE 32              // elems per LDS row, no pad; XOR swizzle for banks
#define NSTEP (C_ / BK)      // 16

typedef __attribute__((ext_vector_type(8))) short frag_ab;   // 8 bf16 (4 VGPRs)
typedef __attribute__((ext_vector_type(4))) float frag_cd;   // 4 fp32

// RNE float -> bf16 (no NaN handling; inputs are finite random data)
__device__ __forceinline__ unsigned short f2bf(float f) {
    union { float f; uint32_t u; } v; v.f = f;
    uint32_t u = v.u;
    return (unsigned short)((u + 0x7FFFu + ((u >> 16) & 1u)) >> 16);
}

__device__ __forceinline__ void cvt4_store(unsigned short* dst, float4 v) {
    union { unsigned short u[4]; uint2 d; } p;
    p.u[0] = f2bf(v.x); p.u[1] = f2bf(v.y); p.u[2] = f2bf(v.z); p.u[3] = f2bf(v.w);
    *(uint2*)dst = p.d;   // 8 B aligned
}

__global__ __launch_bounds__(256, 4)
void NeuralEmbeddingLayer_kernel(
    const float* __restrict__ features,     // [B,T,C]
    const int*   __restrict__ ts,           // [B,T]
    const int*   __restrict__ date_idx,     // [B]
    const float* __restrict__ spikes,       // [N_DATES,H,C]
    const float* __restrict__ spikes_bias,  // [N_DATES]
    const float* __restrict__ pos,          // [MAX_F,H]
    float*       __restrict__ out)          // [B,T,H]
{
    const int tid = threadIdx.x;
    const int bid = blockIdx.x;

    // XCD-clustered mapping: blocks are dealt round-robin to XCDs (xcd = bid%8).
    // Give each XCD whole samples: one sample's A+B working set (2+2 MB) fits
    // its 4 MB private L2, and its 64 tiles are co-resident (4 blocks/CU x 32 CU).
    const int xcd   = bid & 7;
    const int local = bid >> 3;               // 0..255 within this XCD
    const int b     = ((local >> 6) << 3) + xcd;  // 4 samples per XCD
    const int tile  = local & 63;
    const int ttile = tile >> 3;
    const int htile = tile & 7;
    const int t0 = ttile * BM;
    const int h0 = htile * BN;

    const int   date = date_idx[b];
    const float bias = spikes_bias[date];
    const float* A = features + ((size_t)b * T_ + t0) * C_;     // row stride C_
    const float* W = spikes   + ((size_t)date * H_ + h0) * C_;  // row stride C_

    __shared__ __align__(16) unsigned short ldsA[2][BM * ROWE]; // 8 KB each
    __shared__ __align__(16) unsigned short ldsB[2][BM * ROWE];
    __shared__ int lds_ts[BM];

    if (tid < BM) lds_ts[tid] = ts[b * T_ + t0 + tid];

    // ---- staging helpers ----
    // tile: 128 rows x 8 float4-groups = 1024 groups; 256 threads -> 4 each
    float4 pfA[4], pfB[4];

    auto gload = [&](const float* __restrict__ base, int i, int k0) -> float4 {
        int g = i * 256 + tid;
        int row = g >> 3, k4 = g & 7;
        return *(const float4*)(base + (size_t)row * C_ + k0 + k4 * 4);
    };
    // XOR-swizzled LDS offset for a 4-elem (8 B) group: 16B-group index j>>1
    // is swizzled by (row>>1)&3 -> ds_write_b64/ds_read_b128 both hit the
    // 128/256-dword-per-wave minimum cycle count (2-way max aliasing).
    auto stage = [&](int buf) {
#pragma unroll
        for (int i = 0; i < 4; ++i) {
            int g = i * 256 + tid;
            int row = g >> 3, j = g & 7;
            int s = (j >> 1) ^ ((row >> 1) & 3);
            int off = row * ROWE + s * 8 + (j & 1) * 4;
            cvt4_store(&ldsA[buf][off], pfA[i]);
            cvt4_store(&ldsB[buf][off], pfB[i]);
        }
    };

    // ---- prologue: K-step 0 ----
#pragma unroll
    for (int i = 0; i < 4; ++i) { pfA[i] = gload(A, i, 0); pfB[i] = gload(W, i, 0); }
    stage(0);
    __syncthreads();

    // ---- wave/lane decode ----
    const int wave = tid >> 6;
    const int lane = tid & 63;
    const int quad = lane >> 4;       // k-halfgroup for A/B frags; row-quad for C/D
    const int m_   = lane & 15;
    const int wm = (wave >> 1) * 64;  // wave tile origin in M (t)
    const int wn = (wave & 1) * 64;   // in N (h)

    frag_cd acc[4][4] = {};

    // ---- K loop: double-buffered LDS, register prefetch ----
    for (int ks = 0; ks < NSTEP; ++ks) {
        const int buf = ks & 1;
        if (ks + 1 < NSTEP) {
            const int k0 = (ks + 1) * BK;
#pragma unroll
            for (int i = 0; i < 4; ++i) { pfA[i] = gload(A, i, k0); pfB[i] = gload(W, i, k0); }
        }

        frag_ab afrag[4], bfrag[4];
#pragma unroll
        for (int mi = 0; mi < 4; ++mi) {
            int row = wm + mi * 16 + m_;
            int sw  = (row >> 1) & 3;
            afrag[mi] = *(const frag_ab*)&ldsA[buf][row * ROWE + ((quad ^ sw) * 8)];
        }
#pragma unroll
        for (int ni = 0; ni < 4; ++ni) {
            int row = wn + ni * 16 + m_;
            int sw  = (row >> 1) & 3;
            bfrag[ni] = *(const frag_ab*)&ldsB[buf][row * ROWE + ((quad ^ sw) * 8)];
        }
#pragma unroll
        for (int mi = 0; mi < 4; ++mi)
#pragma unroll
            for (int ni = 0; ni < 4; ++ni)
                acc[mi][ni] = __builtin_amdgcn_mfma_f32_16x16x32_bf16(
                    afrag[mi], bfrag[ni], acc[mi][ni], 0, 0, 0);

        if (ks + 1 < NSTEP) stage((ks + 1) & 1);
        __syncthreads();
    }

    // ---- epilogue: acc*SCALE + bias + pos[ts[t]][h] ----
    // C/D layout (m89-verified): col = lane&15 (n/h), row = quad*4 + reg (m/t)
#pragma unroll
    for (int mi = 0; mi < 4; ++mi) {
#pragma unroll
        for (int r = 0; r < 4; ++r) {
            int trow = wm + mi * 16 + quad * 4 + r;
            int tsv  = lds_ts[trow];
            const float* prow = pos + (size_t)tsv * H_ + h0;
            size_t orow = ((size_t)b * T_ + (t0 + trow)) * (size_t)H_ + h0;
#pragma unroll
            for (int ni = 0; ni < 4; ++ni) {
                int col = wn + ni * 16 + m_;
                out[orow + col] = acc[mi][ni][r] * SCALE_ + bias + prow[col];
            }
        }
    }
}

extern "C" void kernel_launch(void* const* d_in, const int* in_sizes, int n_in,
                              void* d_out, int out_size, void* d_ws, size_t ws_size,
                              hipStream_t stream) {
    const float* features  = (const float*)d_in[0];
    const int*   ts        = (const int*)d_in[1];
    const int*   date_idx  = (const int*)d_in[2];
    const float* spikes    = (const float*)d_in[3];
    const float* sbias     = (const float*)d_in[4];
    const float* pos       = (const float*)d_in[5];
    float*       out       = (float*)d_out;

    dim3 grid(B_ * (T_ / BM) * (H_ / BN));   // 32 * 8 * 8 = 2048
    NeuralEmbeddingLayer_kernel<<<grid, 256, 0, stream>>>(
        features, ts, date_idx, spikes, sbias, pos, out);
}